// Round 1
// baseline (159.377 us; speedup 1.0000x reference)
//
#include <hip/hip_runtime.h>

// FeatureExtractor: out = concat([x, |ifft2(low)|/max, |ifft2(high)|/max], axis=1)
// x: (32,3,512,512) fp32. Mask keeps 45 freq bins (|ky|,|kx|<=3, ky^2+kx^2<16).
// low-pass signal s is REAL (symmetric mask, real input); hp = |x - s|.
// F[ky][kxs], ky=0..3, kxs=0..6 (kx=kxs-3); negative ky via conjugate symmetry.

#define NN 512
#define IMGS 96
constexpr float TWOPI_N = 6.2831853071795864769f / 512.0f;
constexpr float INV_N2  = 1.0f / (512.0f * 512.0f);

// workspace layout (bytes)
#define G_OFF   0                        // 96*512*8 floats = 1,572,864 B
#define F_OFF   (96 * 512 * 8 * 4)       // 96*56 floats = 21,504 B
#define MAX_OFF (F_OFF + 96 * 56 * 4)    // 2 uints
#define WS_NEEDED (MAX_OFF + 8)

// ---------------- K1: per-row DFT at kx=0..3 ----------------
__global__ __launch_bounds__(64) void k1_rowfft(const float* __restrict__ x,
                                                float* __restrict__ G) {
  const int row = blockIdx.x;
  const int img = blockIdx.y;
  const int tid = threadIdx.x;
  const float* xr = x + (((size_t)img) << 18) + row * NN;

  float gr0 = 0.f, gr1 = 0.f, gi1 = 0.f, gr2 = 0.f, gi2 = 0.f, gr3 = 0.f, gi3 = 0.f;
  // unit-step twiddle e^{+i*2pi/512}
  const float cd = 0.99992470183914454f;
  const float sd = 0.012271538285719925f;
  #pragma unroll
  for (int half = 0; half < 2; ++half) {
    const int v0 = half * 256 + tid * 4;
    const float4 xv = *reinterpret_cast<const float4*>(xr + v0);
    float c, s;
    __sincosf(TWOPI_N * (float)v0, &s, &c);
    const float xe[4] = {xv.x, xv.y, xv.z, xv.w};
    #pragma unroll
    for (int j = 0; j < 4; ++j) {
      const float c2 = c * c - s * s, s2 = 2.f * c * s;
      const float c3 = c * c2 - s * s2, s3 = s * c2 + c * s2;
      const float xx = xe[j];
      gr0 += xx;
      gr1 = fmaf(xx, c,  gr1);  gi1 = fmaf(-xx, s,  gi1);   // e^{-i*1*theta}
      gr2 = fmaf(xx, c2, gr2);  gi2 = fmaf(-xx, s2, gi2);
      gr3 = fmaf(xx, c3, gr3);  gi3 = fmaf(-xx, s3, gi3);
      const float cn = c * cd - s * sd;
      const float sn = s * cd + c * sd;
      c = cn; s = sn;
    }
  }
  #pragma unroll
  for (int off = 32; off; off >>= 1) {
    gr0 += __shfl_down(gr0, off);
    gr1 += __shfl_down(gr1, off); gi1 += __shfl_down(gi1, off);
    gr2 += __shfl_down(gr2, off); gi2 += __shfl_down(gi2, off);
    gr3 += __shfl_down(gr3, off); gi3 += __shfl_down(gi3, off);
  }
  if (tid == 0) {
    float* g = G + (size_t)(img * 512 + row) * 8;
    *reinterpret_cast<float4*>(g)     = make_float4(gr0, 0.f, gr1, gi1);
    *reinterpret_cast<float4*>(g + 4) = make_float4(gr2, gi2, gr3, gi3);
  }
}

// ---------------- K2: column DFT G -> F (per image) ----------------
__global__ __launch_bounds__(256) void k2_colfft(const float* __restrict__ G,
                                                 float* __restrict__ F) {
  const int img = blockIdx.x;
  const int tid = threadIdx.x;
  float Fr[28], Fi[28];
  #pragma unroll
  for (int f = 0; f < 28; ++f) { Fr[f] = 0.f; Fi[f] = 0.f; }

  #pragma unroll
  for (int half = 0; half < 2; ++half) {
    const int u = half * 256 + tid;
    const float* g = G + (size_t)(img * 512 + u) * 8;
    const float4 ga = *reinterpret_cast<const float4*>(g);
    const float4 gb = *reinterpret_cast<const float4*>(g + 4);
    const float Gr[4] = {ga.x, ga.z, gb.x, gb.z};
    const float Gi[4] = {0.f,  ga.w, gb.y, gb.w};
    float cu, su;
    __sincosf(TWOPI_N * (float)u, &su, &cu);
    float pc[4], ps[4];
    pc[0] = 1.f; ps[0] = 0.f;
    pc[1] = cu;  ps[1] = su;
    pc[2] = cu * cu - su * su; ps[2] = 2.f * cu * su;
    pc[3] = pc[1] * pc[2] - ps[1] * ps[2];
    ps[3] = ps[1] * pc[2] + pc[1] * ps[2];
    #pragma unroll
    for (int ky = 0; ky < 4; ++ky) {
      const float c = pc[ky], s = ps[ky];   // use e^{-i ky u th} = (c, -s)
      #pragma unroll
      for (int kxs = 0; kxs < 7; ++kxs) {
        const int a = (kxs < 3) ? (3 - kxs) : (kxs - 3);
        const float gr = Gr[a];
        const float gi = (kxs < 3) ? -Gi[a] : Gi[a];   // G[u,-k] = conj(G[u,k])
        const int f = ky * 7 + kxs;
        Fr[f] += gr * c + gi * s;
        Fi[f] += gi * c - gr * s;
      }
    }
  }
  __shared__ float sm[4][56];
  const int lane = tid & 63;
  const int wv = tid >> 6;
  #pragma unroll
  for (int f = 0; f < 28; ++f) {
    float fr = Fr[f], fi = Fi[f];
    #pragma unroll
    for (int off = 32; off; off >>= 1) {
      fr += __shfl_down(fr, off);
      fi += __shfl_down(fi, off);
    }
    if (lane == 0) { sm[wv][f * 2] = fr; sm[wv][f * 2 + 1] = fi; }
  }
  __syncthreads();
  if (tid < 56) {
    F[img * 56 + tid] = sm[0][tid] + sm[1][tid] + sm[2][tid] + sm[3][tid];
  }
}

// ---------------- shared reconstruction helper ----------------
// Per-thread row tables R_ky[x] for its 4 x positions (y-independent).
__device__ __forceinline__ void build_R(const float* __restrict__ Fimg, int x0,
    float R0[4], float R1r[4], float R1i[4], float R2r[4], float R2i[4],
    float R3r[4], float R3i[4]) {
  float Fr[28], Fi[28];
  #pragma unroll
  for (int f = 0; f < 28; ++f) { Fr[f] = Fimg[f * 2]; Fi[f] = Fimg[f * 2 + 1]; }
  #pragma unroll
  for (int j = 0; j < 4; ++j) {
    float c1, s1;
    __sincosf(TWOPI_N * (float)(x0 + j), &s1, &c1);
    const float c2 = c1 * c1 - s1 * s1, s2 = 2.f * c1 * s1;
    const float c3 = c1 * c2 - s1 * s2, s3 = s1 * c2 + c1 * s2;
    const float pc[4] = {1.f, c1, c2, c3};
    const float ps[4] = {0.f, s1, s2, s3};
    #pragma unroll
    for (int ky = 0; ky < 4; ++ky) {
      float rr = 0.f, ri = 0.f;
      #pragma unroll
      for (int kxs = 0; kxs < 7; ++kxs) {
        if (ky == 3 && (kxs == 0 || kxs == 6)) continue;  // 9+9 >= 16 excluded
        const int a = (kxs < 3) ? (3 - kxs) : (kxs - 3);
        const float ec = pc[a];
        const float es = (kxs < 3) ? -ps[a] : ps[a];      // e^{+i kx x th}
        const int f = ky * 7 + kxs;
        rr += Fr[f] * ec - Fi[f] * es;
        ri += Fr[f] * es + Fi[f] * ec;
      }
      if (ky == 0)      { R0[j]  = rr; }
      else if (ky == 1) { R1r[j] = rr; R1i[j] = ri; }
      else if (ky == 2) { R2r[j] = rr; R2i[j] = ri; }
      else              { R3r[j] = rr; R3i[j] = ri; }
    }
  }
}

// ---------------- K3: global maxes of lp and hp ----------------
__global__ __launch_bounds__(256) void k3_maxes(const float* __restrict__ x,
    const float* __restrict__ F, unsigned int* __restrict__ maxes) {
  const int img = blockIdx.y;
  const int tid = threadIdx.x;
  const int xi = (tid & 127) * 4;
  const int p = tid >> 7;
  const int ybase = blockIdx.x * 32;
  float R0[4], R1r[4], R1i[4], R2r[4], R2i[4], R3r[4], R3i[4];
  build_R(F + img * 56, xi, R0, R1r, R1i, R2r, R2i, R3r, R3i);
  const float* xim = x + (((size_t)img) << 18);
  float mlp = 0.f, mhp = 0.f;
  for (int it = 0; it < 16; ++it) {
    const int y = ybase + it * 2 + p;
    float cy1, sy1;
    __sincosf(TWOPI_N * (float)y, &sy1, &cy1);
    const float cy2 = cy1 * cy1 - sy1 * sy1, sy2 = 2.f * cy1 * sy1;
    const float cy3 = cy1 * cy2 - sy1 * sy2, sy3 = sy1 * cy2 + cy1 * sy2;
    const float4 xv = *reinterpret_cast<const float4*>(xim + y * NN + xi);
    const float xe[4] = {xv.x, xv.y, xv.z, xv.w};
    #pragma unroll
    for (int j = 0; j < 4; ++j) {
      float S = R0[j];
      S = fmaf(2.f * R1r[j], cy1, S); S = fmaf(-2.f * R1i[j], sy1, S);
      S = fmaf(2.f * R2r[j], cy2, S); S = fmaf(-2.f * R2i[j], sy2, S);
      S = fmaf(2.f * R3r[j], cy3, S); S = fmaf(-2.f * R3i[j], sy3, S);
      const float sig = S * INV_N2;
      mlp = fmaxf(mlp, fabsf(sig));
      mhp = fmaxf(mhp, fabsf(xe[j] - sig));
    }
  }
  #pragma unroll
  for (int off = 32; off; off >>= 1) {
    mlp = fmaxf(mlp, __shfl_down(mlp, off));
    mhp = fmaxf(mhp, __shfl_down(mhp, off));
  }
  __shared__ float sm[8];
  const int lane = tid & 63, wv = tid >> 6;
  if (lane == 0) { sm[wv * 2] = mlp; sm[wv * 2 + 1] = mhp; }
  __syncthreads();
  if (tid == 0) {
    const float a = fmaxf(fmaxf(sm[0], sm[2]), fmaxf(sm[4], sm[6]));
    const float b = fmaxf(fmaxf(sm[1], sm[3]), fmaxf(sm[5], sm[7]));
    atomicMax(&maxes[0], __float_as_uint(a));   // nonneg floats: bit order == value order
    atomicMax(&maxes[1], __float_as_uint(b));
  }
}

// ---------------- K4: normalize + write all 9 channels ----------------
__global__ __launch_bounds__(256) void k4_write(const float* __restrict__ x,
    const float* __restrict__ F, const unsigned int* __restrict__ maxes,
    float* __restrict__ out) {
  const int img = blockIdx.y;
  const int b = img / 3, c = img - b * 3;
  const int tid = threadIdx.x;
  const int xi = (tid & 127) * 4;
  const int p = tid >> 7;
  const int ybase = blockIdx.x * 32;
  float R0[4], R1r[4], R1i[4], R2r[4], R2i[4], R3r[4], R3i[4];
  build_R(F + img * 56, xi, R0, R1r, R1i, R2r, R2i, R3r, R3i);
  const float inv_lp = 1.f / __uint_as_float(maxes[0]);
  const float inv_hp = 1.f / __uint_as_float(maxes[1]);
  const float* xim = x + (((size_t)img) << 18);
  float* o0 = out + (((size_t)(b * 9 + c)) << 18);
  float* o1 = out + (((size_t)(b * 9 + 3 + c)) << 18);
  float* o2 = out + (((size_t)(b * 9 + 6 + c)) << 18);
  for (int it = 0; it < 16; ++it) {
    const int y = ybase + it * 2 + p;
    float cy1, sy1;
    __sincosf(TWOPI_N * (float)y, &sy1, &cy1);
    const float cy2 = cy1 * cy1 - sy1 * sy1, sy2 = 2.f * cy1 * sy1;
    const float cy3 = cy1 * cy2 - sy1 * sy2, sy3 = sy1 * cy2 + cy1 * sy2;
    const float4 xv = *reinterpret_cast<const float4*>(xim + y * NN + xi);
    const float xe[4] = {xv.x, xv.y, xv.z, xv.w};
    float lp[4], hp[4];
    #pragma unroll
    for (int j = 0; j < 4; ++j) {
      float S = R0[j];
      S = fmaf(2.f * R1r[j], cy1, S); S = fmaf(-2.f * R1i[j], sy1, S);
      S = fmaf(2.f * R2r[j], cy2, S); S = fmaf(-2.f * R2i[j], sy2, S);
      S = fmaf(2.f * R3r[j], cy3, S); S = fmaf(-2.f * R3i[j], sy3, S);
      const float sig = S * INV_N2;
      lp[j] = fabsf(sig) * inv_lp;
      hp[j] = fabsf(xe[j] - sig) * inv_hp;
    }
    const int o = y * NN + xi;
    *reinterpret_cast<float4*>(o0 + o) = xv;
    *reinterpret_cast<float4*>(o1 + o) = make_float4(lp[0], lp[1], lp[2], lp[3]);
    *reinterpret_cast<float4*>(o2 + o) = make_float4(hp[0], hp[1], hp[2], hp[3]);
  }
}

extern "C" void kernel_launch(void* const* d_in, const int* in_sizes, int n_in,
                              void* d_out, int out_size, void* d_ws, size_t ws_size,
                              hipStream_t stream) {
  if (ws_size < (size_t)WS_NEEDED) return;  // loud failure instead of corruption
  const float* x = (const float*)d_in[0];
  float* out = (float*)d_out;
  char* ws = (char*)d_ws;
  float* G = (float*)(ws + G_OFF);
  float* F = (float*)(ws + F_OFF);
  unsigned int* maxes = (unsigned int*)(ws + MAX_OFF);

  hipMemsetAsync(maxes, 0, 8, stream);
  k1_rowfft<<<dim3(512, IMGS), 64, 0, stream>>>(x, G);
  k2_colfft<<<dim3(IMGS), 256, 0, stream>>>(G, F);
  k3_maxes<<<dim3(16, IMGS), 256, 0, stream>>>(x, F, maxes);
  k4_write<<<dim3(16, IMGS), 256, 0, stream>>>(x, F, maxes, out);
}

// Round 2
// 149.826 us; speedup vs baseline: 1.0638x; 1.0638x over previous
//
#include <hip/hip_runtime.h>

// FeatureExtractor: out = concat([x, |ifft2(low)|/max, |ifft2(high)|/max], axis=1)
// x: (32,3,512,512) fp32. Mask keeps 45 freq bins (|ky|,|kx|<=3, ky^2+kx^2<16).
// Low-pass signal s is REAL (symmetric mask, real input); hp = |x - s|.
// Pipeline: K1 row-DFT -> K2 col-DFT + per-x table Rtab -> K3 maxes -> K4 write.

#define NN 512
#define IMGS 96
constexpr float TWOPI_N = 6.2831853071795864769f / 512.0f;
constexpr float INV_N2  = 1.0f / (512.0f * 512.0f);

typedef float f4v __attribute__((ext_vector_type(4)));

// workspace layout (bytes)
#define G_OFF   0                              // 96*512*8 floats = 1,572,864 B
#define R_OFF   (96 * 512 * 8 * 4)             // Rtab: 96*512*8 floats = 1,572,864 B
#define MAX_OFF (R_OFF + 96 * 512 * 8 * 4)     // 2 uints
#define WS_NEEDED (MAX_OFF + 8)

// ---------------- K1: per-row DFT at kx=0..3 (4 rows/block, wave per row) ----
__global__ __launch_bounds__(256) void k1_rowfft(const float* __restrict__ x,
                                                 float* __restrict__ G,
                                                 unsigned int* __restrict__ maxes) {
  const int tid = threadIdx.x;
  if (blockIdx.x == 0 && blockIdx.y == 0 && tid == 0) {
    maxes[0] = 0u; maxes[1] = 0u;   // fold memset into K1 (K3 runs later in stream)
  }
  const int row = blockIdx.x * 4 + (tid >> 6);
  const int lane = tid & 63;
  const int img = blockIdx.y;
  const float* xr = x + (((size_t)img) << 18) + row * NN;

  float gr0 = 0.f, gr1 = 0.f, gi1 = 0.f, gr2 = 0.f, gi2 = 0.f, gr3 = 0.f, gi3 = 0.f;
  // unit-step twiddle e^{+i*2pi/512}
  const float cd = 0.99992470183914454f;
  const float sd = 0.012271538285719925f;
  #pragma unroll
  for (int half = 0; half < 2; ++half) {
    const int v0 = half * 256 + lane * 4;
    const float4 xv = *reinterpret_cast<const float4*>(xr + v0);
    float c, s;
    __sincosf(TWOPI_N * (float)v0, &s, &c);
    const float xe[4] = {xv.x, xv.y, xv.z, xv.w};
    #pragma unroll
    for (int j = 0; j < 4; ++j) {
      const float c2 = c * c - s * s, s2 = 2.f * c * s;
      const float c3 = c * c2 - s * s2, s3 = s * c2 + c * s2;
      const float xx = xe[j];
      gr0 += xx;
      gr1 = fmaf(xx, c,  gr1);  gi1 = fmaf(-xx, s,  gi1);   // e^{-i*1*theta}
      gr2 = fmaf(xx, c2, gr2);  gi2 = fmaf(-xx, s2, gi2);
      gr3 = fmaf(xx, c3, gr3);  gi3 = fmaf(-xx, s3, gi3);
      const float cn = c * cd - s * sd;
      const float sn = s * cd + c * sd;
      c = cn; s = sn;
    }
  }
  #pragma unroll
  for (int off = 32; off; off >>= 1) {
    gr0 += __shfl_down(gr0, off);
    gr1 += __shfl_down(gr1, off); gi1 += __shfl_down(gi1, off);
    gr2 += __shfl_down(gr2, off); gi2 += __shfl_down(gi2, off);
    gr3 += __shfl_down(gr3, off); gi3 += __shfl_down(gi3, off);
  }
  if (lane == 0) {
    float* g = G + (size_t)(img * 512 + row) * 8;
    *reinterpret_cast<float4*>(g)     = make_float4(gr0, 0.f, gr1, gi1);
    *reinterpret_cast<float4*>(g + 4) = make_float4(gr2, gi2, gr3, gi3);
  }
}

// ---------------- K2: column DFT G -> F (LDS) -> per-x table Rtab ------------
__global__ __launch_bounds__(256) void k2_colfft(const float* __restrict__ G,
                                                 float* __restrict__ Rtab) {
  const int img = blockIdx.x;
  const int tid = threadIdx.x;
  float Fr[28], Fi[28];
  #pragma unroll
  for (int f = 0; f < 28; ++f) { Fr[f] = 0.f; Fi[f] = 0.f; }

  #pragma unroll
  for (int half = 0; half < 2; ++half) {
    const int u = half * 256 + tid;
    const float* g = G + (size_t)(img * 512 + u) * 8;
    const float4 ga = *reinterpret_cast<const float4*>(g);
    const float4 gb = *reinterpret_cast<const float4*>(g + 4);
    const float Gr[4] = {ga.x, ga.z, gb.x, gb.z};
    const float Gi[4] = {0.f,  ga.w, gb.y, gb.w};
    float cu, su;
    __sincosf(TWOPI_N * (float)u, &su, &cu);
    float pc[4], ps[4];
    pc[0] = 1.f; ps[0] = 0.f;
    pc[1] = cu;  ps[1] = su;
    pc[2] = cu * cu - su * su; ps[2] = 2.f * cu * su;
    pc[3] = pc[1] * pc[2] - ps[1] * ps[2];
    ps[3] = ps[1] * pc[2] + pc[1] * ps[2];
    #pragma unroll
    for (int ky = 0; ky < 4; ++ky) {
      const float c = pc[ky], s = ps[ky];   // e^{-i ky u th} = (c, -s)
      #pragma unroll
      for (int kxs = 0; kxs < 7; ++kxs) {
        const int a = (kxs < 3) ? (3 - kxs) : (kxs - 3);
        const float gr = Gr[a];
        const float gi = (kxs < 3) ? -Gi[a] : Gi[a];   // G[u,-k] = conj(G[u,k])
        const int f = ky * 7 + kxs;
        Fr[f] += gr * c + gi * s;
        Fi[f] += gi * c - gr * s;
      }
    }
  }
  __shared__ float sm[4][56];
  __shared__ float Ff[56];
  const int lane = tid & 63;
  const int wv = tid >> 6;
  #pragma unroll
  for (int f = 0; f < 28; ++f) {
    float fr = Fr[f], fi = Fi[f];
    #pragma unroll
    for (int off = 32; off; off >>= 1) {
      fr += __shfl_down(fr, off);
      fi += __shfl_down(fi, off);
    }
    if (lane == 0) { sm[wv][f * 2] = fr; sm[wv][f * 2 + 1] = fi; }
  }
  __syncthreads();
  if (tid < 56) {
    Ff[tid] = sm[0][tid] + sm[1][tid] + sm[2][tid] + sm[3][tid];
  }
  __syncthreads();

  // per-x reconstruction table: Rtab[x][8] = (R0, 2R1r, 2R1i, 2R2r, 2R2i, 2R3r, 2R3i, 0) / N^2
  float fr[28], fi[28];
  #pragma unroll
  for (int f = 0; f < 28; ++f) { fr[f] = Ff[2 * f]; fi[f] = Ff[2 * f + 1]; }
  #pragma unroll
  for (int half = 0; half < 2; ++half) {
    const int xx = half * 256 + tid;
    float c1, s1;
    __sincosf(TWOPI_N * (float)xx, &s1, &c1);
    const float c2 = c1 * c1 - s1 * s1, s2 = 2.f * c1 * s1;
    const float c3 = c1 * c2 - s1 * s2, s3 = s1 * c2 + c1 * s2;
    const float pc[4] = {1.f, c1, c2, c3};
    const float ps[4] = {0.f, s1, s2, s3};
    float Rr[4], Ri[4];
    #pragma unroll
    for (int ky = 0; ky < 4; ++ky) {
      float rr = 0.f, ri = 0.f;
      #pragma unroll
      for (int kxs = 0; kxs < 7; ++kxs) {
        if (ky == 3 && (kxs == 0 || kxs == 6)) continue;  // 9+9 >= 16 excluded
        const int a = (kxs < 3) ? (3 - kxs) : (kxs - 3);
        const float ec = pc[a];
        const float es = (kxs < 3) ? -ps[a] : ps[a];      // e^{+i kx x th}
        const int f = ky * 7 + kxs;
        rr += fr[f] * ec - fi[f] * es;
        ri += fr[f] * es + fi[f] * ec;
      }
      Rr[ky] = rr; Ri[ky] = ri;
    }
    float* o = Rtab + (size_t)(img * 512 + xx) * 8;
    const float k2s = 2.f * INV_N2;
    *reinterpret_cast<float4*>(o) =
        make_float4(Rr[0] * INV_N2, Rr[1] * k2s, Ri[1] * k2s, Rr[2] * k2s);
    *reinterpret_cast<float4*>(o + 4) =
        make_float4(Ri[2] * k2s, Rr[3] * k2s, Ri[3] * k2s, 0.f);
  }
}

// ---------------- shared per-block prologue for K3/K4 ----------------
__device__ __forceinline__ void load_ctx(const float* __restrict__ Rtab, int img,
                                         int xi, int ybase, int tid,
                                         float (*yt)[6], float4 Ra[4], float4 Rb[4]) {
  if (tid < 32) {
    const int y = ybase + tid;
    float c1, s1;
    __sincosf(TWOPI_N * (float)y, &s1, &c1);
    const float c2 = c1 * c1 - s1 * s1, s2 = 2.f * c1 * s1;
    const float c3 = c1 * c2 - s1 * s2, s3 = s1 * c2 + c1 * s2;
    yt[tid][0] = c1; yt[tid][1] = s1;
    yt[tid][2] = c2; yt[tid][3] = s2;
    yt[tid][4] = c3; yt[tid][5] = s3;
  }
  const float* rt = Rtab + (size_t)(img * 512 + xi) * 8;
  #pragma unroll
  for (int j = 0; j < 4; ++j) {
    Ra[j] = *reinterpret_cast<const float4*>(rt + j * 8);
    Rb[j] = *reinterpret_cast<const float4*>(rt + j * 8 + 4);
  }
  __syncthreads();
}

__device__ __forceinline__ float recon(const float4& Ra, const float4& Rb,
                                       const float* yy) {
  float S = Ra.x;
  S = fmaf(Ra.y,  yy[0], S); S = fmaf(-Ra.z, yy[1], S);
  S = fmaf(Ra.w,  yy[2], S); S = fmaf(-Rb.x, yy[3], S);
  S = fmaf(Rb.y,  yy[4], S); S = fmaf(-Rb.z, yy[5], S);
  return S;
}

// ---------------- K3: global maxes of lp and hp ----------------
__global__ __launch_bounds__(256) void k3_maxes(const float* __restrict__ x,
    const float* __restrict__ Rtab, unsigned int* __restrict__ maxes) {
  const int img = blockIdx.y;
  const int tid = threadIdx.x;
  const int xi = (tid & 127) * 4;
  const int p = tid >> 7;
  const int ybase = blockIdx.x * 32;
  __shared__ float yt[32][6];
  float4 Ra[4], Rb[4];
  load_ctx(Rtab, img, xi, ybase, tid, yt, Ra, Rb);

  const float* xim = x + (((size_t)img) << 18);
  float mlp = 0.f, mhp = 0.f;
  for (int it = 0; it < 16; ++it) {
    const int yy = it * 2 + p;
    const int y = ybase + yy;
    float yv[6];
    #pragma unroll
    for (int q = 0; q < 6; ++q) yv[q] = yt[yy][q];
    const float4 xv = *reinterpret_cast<const float4*>(xim + y * NN + xi);
    const float xe[4] = {xv.x, xv.y, xv.z, xv.w};
    #pragma unroll
    for (int j = 0; j < 4; ++j) {
      const float sig = recon(Ra[j], Rb[j], yv);
      mlp = fmaxf(mlp, fabsf(sig));
      mhp = fmaxf(mhp, fabsf(xe[j] - sig));
    }
  }
  #pragma unroll
  for (int off = 32; off; off >>= 1) {
    mlp = fmaxf(mlp, __shfl_down(mlp, off));
    mhp = fmaxf(mhp, __shfl_down(mhp, off));
  }
  __shared__ float sm[8];
  const int lane = tid & 63, wv = tid >> 6;
  if (lane == 0) { sm[wv * 2] = mlp; sm[wv * 2 + 1] = mhp; }
  __syncthreads();
  if (tid == 0) {
    const float a = fmaxf(fmaxf(sm[0], sm[2]), fmaxf(sm[4], sm[6]));
    const float b = fmaxf(fmaxf(sm[1], sm[3]), fmaxf(sm[5], sm[7]));
    atomicMax(&maxes[0], __float_as_uint(a));   // nonneg floats: bit order == value order
    atomicMax(&maxes[1], __float_as_uint(b));
  }
}

// ---------------- K4: normalize + write all 9 channels ----------------
__global__ __launch_bounds__(256) void k4_write(const float* __restrict__ x,
    const float* __restrict__ Rtab, const unsigned int* __restrict__ maxes,
    float* __restrict__ out) {
  const int img = blockIdx.y;
  const int b = img / 3, c = img - b * 3;
  const int tid = threadIdx.x;
  const int xi = (tid & 127) * 4;
  const int p = tid >> 7;
  const int ybase = blockIdx.x * 32;
  __shared__ float yt[32][6];
  float4 Ra[4], Rb[4];
  load_ctx(Rtab, img, xi, ybase, tid, yt, Ra, Rb);

  const float inv_lp = 1.f / __uint_as_float(maxes[0]);
  const float inv_hp = 1.f / __uint_as_float(maxes[1]);
  const float* xim = x + (((size_t)img) << 18);
  float* o0 = out + (((size_t)(b * 9 + c)) << 18);
  float* o1 = out + (((size_t)(b * 9 + 3 + c)) << 18);
  float* o2 = out + (((size_t)(b * 9 + 6 + c)) << 18);
  for (int it = 0; it < 16; ++it) {
    const int yy = it * 2 + p;
    const int y = ybase + yy;
    float yv[6];
    #pragma unroll
    for (int q = 0; q < 6; ++q) yv[q] = yt[yy][q];
    const float4 xv = *reinterpret_cast<const float4*>(xim + y * NN + xi);
    const float xe[4] = {xv.x, xv.y, xv.z, xv.w};
    f4v lpv, hpv, xvv;
    #pragma unroll
    for (int j = 0; j < 4; ++j) {
      const float sig = recon(Ra[j], Rb[j], yv);
      lpv[j] = fabsf(sig) * inv_lp;
      hpv[j] = fabsf(xe[j] - sig) * inv_hp;
      xvv[j] = xe[j];
    }
    const int o = y * NN + xi;
    __builtin_nontemporal_store(xvv, reinterpret_cast<f4v*>(o0 + o));
    __builtin_nontemporal_store(lpv, reinterpret_cast<f4v*>(o1 + o));
    __builtin_nontemporal_store(hpv, reinterpret_cast<f4v*>(o2 + o));
  }
}

extern "C" void kernel_launch(void* const* d_in, const int* in_sizes, int n_in,
                              void* d_out, int out_size, void* d_ws, size_t ws_size,
                              hipStream_t stream) {
  if (ws_size < (size_t)WS_NEEDED) return;  // loud failure instead of corruption
  const float* x = (const float*)d_in[0];
  float* out = (float*)d_out;
  char* ws = (char*)d_ws;
  float* G = (float*)(ws + G_OFF);
  float* Rtab = (float*)(ws + R_OFF);
  unsigned int* maxes = (unsigned int*)(ws + MAX_OFF);

  k1_rowfft<<<dim3(128, IMGS), 256, 0, stream>>>(x, G, maxes);
  k2_colfft<<<dim3(IMGS), 256, 0, stream>>>(G, Rtab);
  k3_maxes<<<dim3(16, IMGS), 256, 0, stream>>>(x, Rtab, maxes);
  k4_write<<<dim3(16, IMGS), 256, 0, stream>>>(x, Rtab, maxes, out);
}